// Round 1
// baseline (1752.894 us; speedup 1.0000x reference)
//
#include <hip/hip_runtime.h>
#include <hip/hip_bf16.h>
#include <cmath>

#define N_ROI 2048
#define PER_IMG 256
#define NIMG 8
#define NCH 256
#define ROUT 7
#define KFEAT (NCH * ROUT * ROUT)   // 12544
#define CMID 1024
#define IMSZ 640
#define IMTOP 100
#define SCORE_THR 0.05f
#define IOU_THR 0.5f
#define BBOX_CLAMP 4.135166556742356f   // log(1000/16)

// ----------------------------------------------------------------------------
// RoI Align: one block per RoI (256 threads = 256 channels), 7x7 bins,
// bilinear from NCHW fmaps. Output layout feat[roi][c*49 + by*7 + bx]
// matching the reference's transpose((0,3,1,2)).reshape(n,-1).
// ----------------------------------------------------------------------------
__global__ __launch_bounds__(256) void roi_align_kernel(
    const float* __restrict__ prop, const int* __restrict__ imidx,
    const float* __restrict__ f0, const float* __restrict__ f1,
    const float* __restrict__ f2, const float* __restrict__ f3,
    float* __restrict__ feat)
{
    const int roi = blockIdx.x;
    const int c = threadIdx.x;
    const float x1 = prop[roi * 4 + 0], y1 = prop[roi * 4 + 1];
    const float x2 = prop[roi * 4 + 2], y2 = prop[roi * 4 + 3];
    const float area = fmaxf(x2 - x1, 0.f) * fmaxf(y2 - y1, 0.f);
    float lf = floorf(4.0f + log2f(sqrtf(area) / 224.0f + 1e-8f));
    lf = fminf(fmaxf(lf, 2.0f), 5.0f);
    const int lvl = (int)lf - 2;                 // 0..3
    const int stride = 4 << lvl;                 // 4,8,16,32
    const int H = IMSZ / stride;
    const int W = H;
    const float* fm = (lvl == 0) ? f0 : (lvl == 1) ? f1 : (lvl == 2) ? f2 : f3;
    const float sc = 1.0f / (float)stride;
    const int img = imidx[roi];
    const float* base = fm + ((size_t)(img * NCH + c)) * (size_t)(H * W);
    const float stepx = (x2 - x1) * sc * (1.0f / ROUT);
    const float stepy = (y2 - y1) * sc * (1.0f / ROUT);
    const float ox = x1 * sc, oy = y1 * sc;
    float* orow = feat + (size_t)roi * KFEAT + (size_t)c * (ROUT * ROUT);

    for (int by = 0; by < ROUT; by++) {
        float py = oy + ((float)by + 0.5f) * stepy;
        float y = fminf(fmaxf(py, 0.f), (float)(H - 1));
        float y0 = floorf(y);
        int yi0 = (int)y0;
        int yi1 = min(yi0 + 1, H - 1);
        float fy = y - y0;
        for (int bx = 0; bx < ROUT; bx++) {
            float px = ox + ((float)bx + 0.5f) * stepx;
            float x = fminf(fmaxf(px, 0.f), (float)(W - 1));
            float x0 = floorf(x);
            int xi0 = (int)x0;
            int xi1 = min(xi0 + 1, W - 1);
            float fx = x - x0;
            float v00 = base[yi0 * W + xi0];
            float v01 = base[yi0 * W + xi1];
            float v10 = base[yi1 * W + xi0];
            float v11 = base[yi1 * W + xi1];
            float v = v00 * ((1.f - fy) * (1.f - fx))
                    + v01 * ((1.f - fy) * fx)
                    + v10 * (fy * (1.f - fx))
                    + v11 * (fy * fx);
            orow[by * ROUT + bx] = v;
        }
    }
}

// ----------------------------------------------------------------------------
// fp32 GEMM: C[M,N] = relu(A[M,K] @ W[N,K]^T + bias). Both operands K-major.
// 64x64 tile, BK=32, 256 threads, 4x4 per thread. LDS stored [k][m]/[k][n]
// with pad to 68 floats (16B-aligned rows, conflict-light).
// ----------------------------------------------------------------------------
#define BM 64
#define BN 64
#define BK 32
#define BMP 68

__global__ __launch_bounds__(256) void gemm_relu_kernel(
    const float* __restrict__ A, const float* __restrict__ Wt,
    const float* __restrict__ bias, float* __restrict__ Cout,
    int M, int N, int K, int do_relu)
{
    __shared__ float As[BK * BMP];
    __shared__ float Bs[BK * BMP];
    const int tid = threadIdx.x;
    const int bm = blockIdx.x * BM;
    const int bn = blockIdx.y * BN;
    const int tm = (tid & 15) * 4;
    const int tn = (tid >> 4) * 4;
    const int rowA = tid >> 3;        // 0..31
    const int kq = (tid & 7) * 4;     // 0,4,...,28

    float acc[4][4] = {};

    const float* Aptr = A + (size_t)(bm + rowA) * K + kq;
    const float* Bptr = Wt + (size_t)(bn + rowA) * K + kq;
    const size_t rowStep = (size_t)32 * K;

    for (int k0 = 0; k0 < K; k0 += BK) {
        float4 a0 = *(const float4*)(Aptr + k0);
        float4 a1 = *(const float4*)(Aptr + k0 + rowStep);
        float4 b0 = *(const float4*)(Bptr + k0);
        float4 b1 = *(const float4*)(Bptr + k0 + rowStep);
        __syncthreads();   // previous iteration's LDS reads done
        As[(kq + 0) * BMP + rowA] = a0.x;
        As[(kq + 1) * BMP + rowA] = a0.y;
        As[(kq + 2) * BMP + rowA] = a0.z;
        As[(kq + 3) * BMP + rowA] = a0.w;
        As[(kq + 0) * BMP + rowA + 32] = a1.x;
        As[(kq + 1) * BMP + rowA + 32] = a1.y;
        As[(kq + 2) * BMP + rowA + 32] = a1.z;
        As[(kq + 3) * BMP + rowA + 32] = a1.w;
        Bs[(kq + 0) * BMP + rowA] = b0.x;
        Bs[(kq + 1) * BMP + rowA] = b0.y;
        Bs[(kq + 2) * BMP + rowA] = b0.z;
        Bs[(kq + 3) * BMP + rowA] = b0.w;
        Bs[(kq + 0) * BMP + rowA + 32] = b1.x;
        Bs[(kq + 1) * BMP + rowA + 32] = b1.y;
        Bs[(kq + 2) * BMP + rowA + 32] = b1.z;
        Bs[(kq + 3) * BMP + rowA + 32] = b1.w;
        __syncthreads();
#pragma unroll
        for (int k = 0; k < BK; k++) {
            float4 av = *(const float4*)&As[k * BMP + tm];
            float4 bv = *(const float4*)&Bs[k * BMP + tn];
            acc[0][0] += av.x * bv.x; acc[0][1] += av.x * bv.y;
            acc[0][2] += av.x * bv.z; acc[0][3] += av.x * bv.w;
            acc[1][0] += av.y * bv.x; acc[1][1] += av.y * bv.y;
            acc[1][2] += av.y * bv.z; acc[1][3] += av.y * bv.w;
            acc[2][0] += av.z * bv.x; acc[2][1] += av.z * bv.y;
            acc[2][2] += av.z * bv.z; acc[2][3] += av.z * bv.w;
            acc[3][0] += av.w * bv.x; acc[3][1] += av.w * bv.y;
            acc[3][2] += av.w * bv.z; acc[3][3] += av.w * bv.w;
        }
    }

    const float bb0 = bias[bn + tn + 0];
    const float bb1 = bias[bn + tn + 1];
    const float bb2 = bias[bn + tn + 2];
    const float bb3 = bias[bn + tn + 3];
#pragma unroll
    for (int i = 0; i < 4; i++) {
        float4 o;
        o.x = acc[i][0] + bb0;
        o.y = acc[i][1] + bb1;
        o.z = acc[i][2] + bb2;
        o.w = acc[i][3] + bb3;
        if (do_relu) {
            o.x = fmaxf(o.x, 0.f); o.y = fmaxf(o.y, 0.f);
            o.z = fmaxf(o.z, 0.f); o.w = fmaxf(o.w, 0.f);
        }
        *(float4*)(Cout + (size_t)(bm + tm + i) * N + bn + tn) = o;
    }
}

// ----------------------------------------------------------------------------
// Heads: one wave per RoI. 6 dot products over CMID (cls0, cls1, reg rows
// 4..7), softmax score, box decode, keep-mask.
// ----------------------------------------------------------------------------
__global__ __launch_bounds__(64) void head_kernel(
    const float* __restrict__ h2, const float* __restrict__ prop,
    const int* __restrict__ imidx, const int* __restrict__ imsizes,
    const float* __restrict__ cls_w, const float* __restrict__ cls_b,
    const float* __restrict__ reg_w, const float* __restrict__ reg_b,
    float* __restrict__ boxes_all, float* __restrict__ scr_all)
{
    const int roi = blockIdx.x;
    const int l = threadIdx.x;
    const float* h = h2 + (size_t)roi * CMID;
    float a0 = 0.f, a1 = 0.f, r0 = 0.f, r1 = 0.f, r2 = 0.f, r3 = 0.f;
    for (int k = l; k < CMID; k += 64) {
        float hv = h[k];
        a0 += hv * cls_w[k];
        a1 += hv * cls_w[CMID + k];
        r0 += hv * reg_w[4 * CMID + k];
        r1 += hv * reg_w[5 * CMID + k];
        r2 += hv * reg_w[6 * CMID + k];
        r3 += hv * reg_w[7 * CMID + k];
    }
    for (int off = 32; off > 0; off >>= 1) {
        a0 += __shfl_down(a0, off);
        a1 += __shfl_down(a1, off);
        r0 += __shfl_down(r0, off);
        r1 += __shfl_down(r1, off);
        r2 += __shfl_down(r2, off);
        r3 += __shfl_down(r3, off);
    }
    if (l == 0) {
        float l0 = a0 + cls_b[0], l1 = a1 + cls_b[1];
        float scr = 1.0f / (1.0f + expf(l0 - l1));   // softmax[:,1]
        float dx = (r0 + reg_b[4]) / 10.0f;
        float dy = (r1 + reg_b[5]) / 10.0f;
        float dw = (r2 + reg_b[6]) / 5.0f;
        float dh = (r3 + reg_b[7]) / 5.0f;
        float x1 = prop[roi * 4 + 0], y1 = prop[roi * 4 + 1];
        float x2 = prop[roi * 4 + 2], y2 = prop[roi * 4 + 3];
        float w = x2 - x1, hh = y2 - y1;
        float cx = x1 + 0.5f * w, cy = y1 + 0.5f * hh;
        float pcx = dx * w + cx, pcy = dy * hh + cy;
        float pw = w * expf(fminf(dw, BBOX_CLAMP));
        float ph = hh * expf(fminf(dh, BBOX_CLAMP));
        int img = imidx[roi];
        float szh = (float)imsizes[img * 2 + 0];
        float szw = (float)imsizes[img * 2 + 1];
        float bx1 = fminf(fmaxf(pcx - 0.5f * pw, 0.f), szw);
        float bx2 = fminf(fmaxf(pcx + 0.5f * pw, 0.f), szw);
        float by1 = fminf(fmaxf(pcy - 0.5f * ph, 0.f), szh);
        float by2 = fminf(fmaxf(pcy + 0.5f * ph, 0.f), szh);
        bool keep = (scr > SCORE_THR) && (bx2 - bx1 >= 1.0f) && (by2 - by1 >= 1.0f);
        boxes_all[roi * 4 + 0] = bx1;
        boxes_all[roi * 4 + 1] = by1;
        boxes_all[roi * 4 + 2] = bx2;
        boxes_all[roi * 4 + 3] = by2;
        scr_all[roi] = keep ? scr : -1.0f;
    }
}

// ----------------------------------------------------------------------------
// NMS: one block per image, 256 threads = 256 boxes. 100 sequential
// selections; argmax with lowest-index tie-break (= jnp first occurrence).
// Writes all outputs: boxes[0:3200], scr[3200:4000], cls[4000:4800],
// valid[4800:5600], all as float32.
// ----------------------------------------------------------------------------
__global__ __launch_bounds__(PER_IMG) void nms_kernel(
    const float* __restrict__ boxes_all, const float* __restrict__ scr_all,
    float* __restrict__ out)
{
    const int img = blockIdx.x;
    const int t = threadIdx.x;
    __shared__ float sbx1[PER_IMG], sby1[PER_IMG], sbx2[PER_IMG], sby2[PER_IMG];
    __shared__ float sarea[PER_IMG];
    __shared__ float sval[PER_IMG];
    __shared__ int sidx[PER_IMG];

    const int g = img * PER_IMG + t;
    float b0 = boxes_all[g * 4 + 0];
    float b1 = boxes_all[g * 4 + 1];
    float b2 = boxes_all[g * 4 + 2];
    float b3 = boxes_all[g * 4 + 3];
    sbx1[t] = b0; sby1[t] = b1; sbx2[t] = b2; sby2[t] = b3;
    float area = fmaxf(b2 - b0, 0.f) * fmaxf(b3 - b1, 0.f);
    sarea[t] = area;
    float scr = scr_all[g];
    __syncthreads();

    for (int it = 0; it < IMTOP; it++) {
        sval[t] = scr;
        sidx[t] = t;
        __syncthreads();
        for (int off = PER_IMG / 2; off > 0; off >>= 1) {
            if (t < off) {
                float v2 = sval[t + off]; int i2 = sidx[t + off];
                float v1 = sval[t];       int i1 = sidx[t];
                if (v2 > v1 || (v2 == v1 && i2 < i1)) { sval[t] = v2; sidx[t] = i2; }
            }
            __syncthreads();
        }
        int sel = sidx[0];
        float s = sval[0];
        float cx1 = sbx1[sel], cy1 = sby1[sel], cx2 = sbx2[sel], cy2 = sby2[sel];
        float ai = sarea[sel];
        if (t == 0) {
            out[(img * IMTOP + it) * 4 + 0] = cx1;
            out[(img * IMTOP + it) * 4 + 1] = cy1;
            out[(img * IMTOP + it) * 4 + 2] = cx2;
            out[(img * IMTOP + it) * 4 + 3] = cy2;
            out[NIMG * IMTOP * 4 + img * IMTOP + it] = fmaxf(s, -1.0f);
            float validf = (s > SCORE_THR) ? 1.0f : 0.0f;
            out[NIMG * IMTOP * 5 + img * IMTOP + it] = validf;  // out_cls
            out[NIMG * IMTOP * 6 + img * IMTOP + it] = validf;  // valid
        }
        // suppress
        float xx1 = fmaxf(cx1, b0), yy1 = fmaxf(cy1, b1);
        float xx2 = fminf(cx2, b2), yy2 = fminf(cy2, b3);
        float inter = fmaxf(xx2 - xx1, 0.f) * fmaxf(yy2 - yy1, 0.f);
        float iou = inter / (ai + area - inter + 1e-6f);
        if (iou > IOU_THR || t == sel) scr = -__builtin_inff();
        __syncthreads();
    }
}

// ----------------------------------------------------------------------------
extern "C" void kernel_launch(void* const* d_in, const int* in_sizes, int n_in,
                              void* d_out, int out_size, void* d_ws, size_t ws_size,
                              hipStream_t stream)
{
    const float* prop  = (const float*)d_in[0];
    const int*   imidx = (const int*)d_in[1];
    const float* f0    = (const float*)d_in[2];
    const float* f1    = (const float*)d_in[3];
    const float* f2    = (const float*)d_in[4];
    const float* f3    = (const float*)d_in[5];
    const int*   imsz  = (const int*)d_in[6];
    const float* fc6w  = (const float*)d_in[7];
    const float* fc6b  = (const float*)d_in[8];
    const float* fc7w  = (const float*)d_in[9];
    const float* fc7b  = (const float*)d_in[10];
    const float* clsw  = (const float*)d_in[11];
    const float* clsb  = (const float*)d_in[12];
    const float* regw  = (const float*)d_in[13];
    const float* regb  = (const float*)d_in[14];

    float* ws = (float*)d_ws;
    float* feat = ws;                                        // 2048*12544
    float* h1 = feat + (size_t)N_ROI * KFEAT;                // 2048*1024
    float* h2 = h1 + (size_t)N_ROI * CMID;                   // 2048*1024
    float* boxes_all = h2 + (size_t)N_ROI * CMID;            // 2048*4
    float* scr_all = boxes_all + (size_t)N_ROI * 4;          // 2048

    roi_align_kernel<<<N_ROI, 256, 0, stream>>>(prop, imidx, f0, f1, f2, f3, feat);

    dim3 g6(N_ROI / BM, CMID / BN);
    gemm_relu_kernel<<<g6, 256, 0, stream>>>(feat, fc6w, fc6b, h1, N_ROI, CMID, KFEAT, 1);
    gemm_relu_kernel<<<g6, 256, 0, stream>>>(h1, fc7w, fc7b, h2, N_ROI, CMID, CMID, 1);

    head_kernel<<<N_ROI, 64, 0, stream>>>(h2, prop, imidx, imsz, clsw, clsb,
                                          regw, regb, boxes_all, scr_all);

    nms_kernel<<<NIMG, PER_IMG, 0, stream>>>(boxes_all, scr_all, (float*)d_out);
}

// Round 2
// 1206.834 us; speedup vs baseline: 1.4525x; 1.4525x over previous
//
#include <hip/hip_runtime.h>
#include <hip/hip_bf16.h>
#include <cmath>

#define N_ROI 2048
#define PER_IMG 256
#define NIMG 8
#define NCH 256
#define ROUT 7
#define KFEAT (NCH * ROUT * ROUT)   // 12544
#define CMID 1024
#define IMSZ 640
#define IMTOP 100
#define SCORE_THR 0.05f
#define IOU_THR 0.5f
#define BBOX_CLAMP 4.135166556742356f   // log(1000/16)

typedef _Float16 half8 __attribute__((ext_vector_type(8)));
typedef float floatx4 __attribute__((ext_vector_type(4)));

#define GLLDS16(gp, lp) \
  __builtin_amdgcn_global_load_lds((const __attribute__((address_space(1))) unsigned int*)(gp), \
                                   (__attribute__((address_space(3))) unsigned int*)(lp), 16, 0, 0)

// ----------------------------------------------------------------------------
// Weight conversion: fp32 -> (hi fp16, lo fp16 scaled by 2^12).
// fc6 variant permutes K from c*49+bin to bin*256+c (matches feat layout).
// ----------------------------------------------------------------------------
__global__ __launch_bounds__(256) void convert_fc6w_kernel(
    const float* __restrict__ w, _Float16* __restrict__ whi, _Float16* __restrict__ wlo)
{
    int idx = blockIdx.x * 256 + threadIdx.x;          // n*12544 + bin*256 + c
    int rem = idx % KFEAT;
    int n = idx / KFEAT;
    int c = rem & 255;
    int bin = rem >> 8;                                 // < 49
    float v = w[(size_t)n * KFEAT + c * (ROUT * ROUT) + bin];
    _Float16 h = (_Float16)v;
    whi[idx] = h;
    wlo[idx] = (_Float16)((v - (float)h) * 4096.0f);
}

__global__ __launch_bounds__(256) void convert_w_kernel(
    const float* __restrict__ w, _Float16* __restrict__ whi, _Float16* __restrict__ wlo)
{
    int idx = blockIdx.x * 256 + threadIdx.x;
    float v = w[idx];
    _Float16 h = (_Float16)v;
    whi[idx] = h;
    wlo[idx] = (_Float16)((v - (float)h) * 4096.0f);
}

// ----------------------------------------------------------------------------
// RoI Align: one block per RoI (256 threads = 256 channels). Output is the
// hi/lo fp16 split in K-order bin*256+c (coalesced 2B stores), matching the
// permuted fc6 weights.
// ----------------------------------------------------------------------------
__global__ __launch_bounds__(256) void roi_align_kernel(
    const float* __restrict__ prop, const int* __restrict__ imidx,
    const float* __restrict__ f0, const float* __restrict__ f1,
    const float* __restrict__ f2, const float* __restrict__ f3,
    _Float16* __restrict__ feat_hi, _Float16* __restrict__ feat_lo)
{
    const int roi = blockIdx.x;
    const int c = threadIdx.x;
    const float x1 = prop[roi * 4 + 0], y1 = prop[roi * 4 + 1];
    const float x2 = prop[roi * 4 + 2], y2 = prop[roi * 4 + 3];
    const float area = fmaxf(x2 - x1, 0.f) * fmaxf(y2 - y1, 0.f);
    float lf = floorf(4.0f + log2f(sqrtf(area) / 224.0f + 1e-8f));
    lf = fminf(fmaxf(lf, 2.0f), 5.0f);
    const int lvl = (int)lf - 2;
    const int stride = 4 << lvl;
    const int H = IMSZ / stride;
    const int W = H;
    const float* fm = (lvl == 0) ? f0 : (lvl == 1) ? f1 : (lvl == 2) ? f2 : f3;
    const float sc = 1.0f / (float)stride;
    const int img = imidx[roi];
    const float* base = fm + ((size_t)(img * NCH + c)) * (size_t)(H * W);
    const float stepx = (x2 - x1) * sc * (1.0f / ROUT);
    const float stepy = (y2 - y1) * sc * (1.0f / ROUT);
    const float ox = x1 * sc, oy = y1 * sc;
    _Float16* ohi = feat_hi + (size_t)roi * KFEAT + c;
    _Float16* olo = feat_lo + (size_t)roi * KFEAT + c;

    for (int by = 0; by < ROUT; by++) {
        float py = oy + ((float)by + 0.5f) * stepy;
        float y = fminf(fmaxf(py, 0.f), (float)(H - 1));
        float y0 = floorf(y);
        int yi0 = (int)y0;
        int yi1 = min(yi0 + 1, H - 1);
        float fy = y - y0;
        for (int bx = 0; bx < ROUT; bx++) {
            float px = ox + ((float)bx + 0.5f) * stepx;
            float x = fminf(fmaxf(px, 0.f), (float)(W - 1));
            float x0 = floorf(x);
            int xi0 = (int)x0;
            int xi1 = min(xi0 + 1, W - 1);
            float fx = x - x0;
            float v00 = base[yi0 * W + xi0];
            float v01 = base[yi0 * W + xi1];
            float v10 = base[yi1 * W + xi0];
            float v11 = base[yi1 * W + xi1];
            float v = v00 * ((1.f - fy) * (1.f - fx))
                    + v01 * ((1.f - fy) * fx)
                    + v10 * (fy * (1.f - fx))
                    + v11 * (fy * fx);
            int bin = by * ROUT + bx;
            _Float16 h = (_Float16)v;
            ohi[bin * 256] = h;
            olo[bin * 256] = (_Float16)((v - (float)h) * 4096.0f);
        }
    }
}

// ----------------------------------------------------------------------------
// Compensated-fp16 GEMM: C_partial = A(M,K) @ B(N,K)^T over K-slice.
// A = Ahi + Alo/4096, B likewise. 3 MFMA chains; fp32-equivalent accuracy.
// 128x128 block tile, 4 waves of 64x64, 16x16x32_f16 MFMA.
// A staged in LDS (hi+lo, XOR-swizzled 16B slots); B frags direct from global.
// ----------------------------------------------------------------------------
__global__ __launch_bounds__(256, 2) void gemm3_kernel(
    const _Float16* __restrict__ Ahi, const _Float16* __restrict__ Alo,
    const _Float16* __restrict__ Bhi, const _Float16* __restrict__ Blo,
    float* __restrict__ part, int M, int N, int K, int Ks)
{
    __shared__ __align__(16) char lds[16384];   // [2 planes][128 rows][64 B]
    const int tid = threadIdx.x;
    const int wave = tid >> 6;
    const int lane = tid & 63;
    const int quad = lane >> 4;
    const int l16 = lane & 15;
    const int wm = wave >> 1, wn = wave & 1;
    const int bm = blockIdx.x * 128;
    const int bn = blockIdx.y * 128;
    const long kbase = (long)blockIdx.z * Ks;

    floatx4 acc1[4][4];
    floatx4 acc2[4][4];
#pragma unroll
    for (int i = 0; i < 4; i++)
#pragma unroll
        for (int j = 0; j < 4; j++) { acc1[i][j] = (floatx4)0.0f; acc2[i][j] = (floatx4)0.0f; }

    const int slot = lane & 3;
    const int srow = lane >> 2;          // 0..15 within a 16-row staging group

    for (int k0 = 0; k0 < Ks; k0 += 32) {
        __syncthreads();
        // ---- stage A hi/lo tile (128 rows x 32 k) via global_load_lds ----
#pragma unroll
        for (int p = 0; p < 2; p++) {
            const _Float16* src = p ? Alo : Ahi;
#pragma unroll
            for (int jj = 0; jj < 2; jj++) {
                int r0 = wave * 32 + jj * 16;
                int r = r0 + srow;
                int cch = slot ^ ((r >> 1) & 3);
                const _Float16* g = src + (size_t)(bm + r) * K + kbase + k0 + cch * 8;
                char* l = lds + p * 8192 + r0 * 64;
                GLLDS16(g, l);
            }
        }
        // ---- B fragments direct from global (overlap with LDS fill) ----
        half8 bh[4], bl[4];
#pragma unroll
        for (int nt = 0; nt < 4; nt++) {
            size_t boff = (size_t)(bn + wn * 64 + nt * 16 + l16) * K + kbase + k0 + quad * 8;
            bh[nt] = *(const half8*)(Bhi + boff);
            bl[nt] = *(const half8*)(Blo + boff);
        }
        __syncthreads();
        // ---- A fragments from LDS ----
        half8 ah[4], al[4];
#pragma unroll
        for (int mt = 0; mt < 4; mt++) {
            int r = wm * 64 + mt * 16 + l16;
            int s = quad ^ ((r >> 1) & 3);
            ah[mt] = *(const half8*)(lds + r * 64 + s * 16);
            al[mt] = *(const half8*)(lds + 8192 + r * 64 + s * 16);
        }
        // ---- 48 MFMAs ----
#pragma unroll
        for (int mt = 0; mt < 4; mt++)
#pragma unroll
            for (int nt = 0; nt < 4; nt++) {
                acc1[mt][nt] = __builtin_amdgcn_mfma_f32_16x16x32_f16(ah[mt], bh[nt], acc1[mt][nt], 0, 0, 0);
                acc2[mt][nt] = __builtin_amdgcn_mfma_f32_16x16x32_f16(ah[mt], bl[nt], acc2[mt][nt], 0, 0, 0);
                acc2[mt][nt] = __builtin_amdgcn_mfma_f32_16x16x32_f16(al[mt], bh[nt], acc2[mt][nt], 0, 0, 0);
            }
    }

    // ---- epilogue: fp32 partials ----
    float* op = part + (size_t)blockIdx.z * M * N;
#pragma unroll
    for (int mt = 0; mt < 4; mt++)
#pragma unroll
        for (int nt = 0; nt < 4; nt++) {
            int n = bn + wn * 64 + nt * 16 + l16;
            int mb = bm + wm * 64 + mt * 16 + quad * 4;
#pragma unroll
            for (int r = 0; r < 4; r++)
                op[(size_t)(mb + r) * N + n] = acc1[mt][nt][r] + acc2[mt][nt][r] * (1.0f / 4096.0f);
        }
}

// ----------------------------------------------------------------------------
// Reductions over split-K partials: bias + relu, then either re-split to
// fp16 hi/lo (FC6 -> h1) or fp32 out (FC7 -> h2).
// ----------------------------------------------------------------------------
__global__ __launch_bounds__(256) void reduce_fc6_kernel(
    const float* __restrict__ part, const float* __restrict__ bias,
    _Float16* __restrict__ h1hi, _Float16* __restrict__ h1lo)
{
    const int MN = N_ROI * CMID;
    int idx = blockIdx.x * 256 + threadIdx.x;
    float v = part[idx] + part[idx + MN] + part[idx + 2 * MN] + part[idx + 3 * MN]
            + bias[idx & (CMID - 1)];
    v = fmaxf(v, 0.f);
    _Float16 h = (_Float16)v;
    h1hi[idx] = h;
    h1lo[idx] = (_Float16)((v - (float)h) * 4096.0f);
}

__global__ __launch_bounds__(256) void reduce_fc7_kernel(
    const float* __restrict__ part, const float* __restrict__ bias,
    float* __restrict__ h2)
{
    const int MN = N_ROI * CMID;
    int idx = blockIdx.x * 256 + threadIdx.x;
    float v = part[idx] + part[idx + MN] + bias[idx & (CMID - 1)];
    h2[idx] = fmaxf(v, 0.f);
}

// ----------------------------------------------------------------------------
// Heads: one wave per RoI (fp32 dot over CMID), softmax score, box decode.
// ----------------------------------------------------------------------------
__global__ __launch_bounds__(64) void head_kernel(
    const float* __restrict__ h2, const float* __restrict__ prop,
    const int* __restrict__ imidx, const int* __restrict__ imsizes,
    const float* __restrict__ cls_w, const float* __restrict__ cls_b,
    const float* __restrict__ reg_w, const float* __restrict__ reg_b,
    float* __restrict__ boxes_all, float* __restrict__ scr_all)
{
    const int roi = blockIdx.x;
    const int l = threadIdx.x;
    const float* h = h2 + (size_t)roi * CMID;
    float a0 = 0.f, a1 = 0.f, r0 = 0.f, r1 = 0.f, r2 = 0.f, r3 = 0.f;
    for (int k = l; k < CMID; k += 64) {
        float hv = h[k];
        a0 += hv * cls_w[k];
        a1 += hv * cls_w[CMID + k];
        r0 += hv * reg_w[4 * CMID + k];
        r1 += hv * reg_w[5 * CMID + k];
        r2 += hv * reg_w[6 * CMID + k];
        r3 += hv * reg_w[7 * CMID + k];
    }
    for (int off = 32; off > 0; off >>= 1) {
        a0 += __shfl_down(a0, off);
        a1 += __shfl_down(a1, off);
        r0 += __shfl_down(r0, off);
        r1 += __shfl_down(r1, off);
        r2 += __shfl_down(r2, off);
        r3 += __shfl_down(r3, off);
    }
    if (l == 0) {
        float l0 = a0 + cls_b[0], l1 = a1 + cls_b[1];
        float scr = 1.0f / (1.0f + expf(l0 - l1));
        float dx = (r0 + reg_b[4]) / 10.0f;
        float dy = (r1 + reg_b[5]) / 10.0f;
        float dw = (r2 + reg_b[6]) / 5.0f;
        float dh = (r3 + reg_b[7]) / 5.0f;
        float x1 = prop[roi * 4 + 0], y1 = prop[roi * 4 + 1];
        float x2 = prop[roi * 4 + 2], y2 = prop[roi * 4 + 3];
        float w = x2 - x1, hh = y2 - y1;
        float cx = x1 + 0.5f * w, cy = y1 + 0.5f * hh;
        float pcx = dx * w + cx, pcy = dy * hh + cy;
        float pw = w * expf(fminf(dw, BBOX_CLAMP));
        float ph = hh * expf(fminf(dh, BBOX_CLAMP));
        int img = imidx[roi];
        float szh = (float)imsizes[img * 2 + 0];
        float szw = (float)imsizes[img * 2 + 1];
        float bx1 = fminf(fmaxf(pcx - 0.5f * pw, 0.f), szw);
        float bx2 = fminf(fmaxf(pcx + 0.5f * pw, 0.f), szw);
        float by1 = fminf(fmaxf(pcy - 0.5f * ph, 0.f), szh);
        float by2 = fminf(fmaxf(pcy + 0.5f * ph, 0.f), szh);
        bool keep = (scr > SCORE_THR) && (bx2 - bx1 >= 1.0f) && (by2 - by1 >= 1.0f);
        boxes_all[roi * 4 + 0] = bx1;
        boxes_all[roi * 4 + 1] = by1;
        boxes_all[roi * 4 + 2] = bx2;
        boxes_all[roi * 4 + 3] = by2;
        scr_all[roi] = keep ? scr : -1.0f;
    }
}

// ----------------------------------------------------------------------------
// NMS: one block per image, 100 sequential argmax selections with
// lowest-index tie-break.
// ----------------------------------------------------------------------------
__global__ __launch_bounds__(PER_IMG) void nms_kernel(
    const float* __restrict__ boxes_all, const float* __restrict__ scr_all,
    float* __restrict__ out)
{
    const int img = blockIdx.x;
    const int t = threadIdx.x;
    __shared__ float sbx1[PER_IMG], sby1[PER_IMG], sbx2[PER_IMG], sby2[PER_IMG];
    __shared__ float sarea[PER_IMG];
    __shared__ float sval[PER_IMG];
    __shared__ int sidx[PER_IMG];

    const int g = img * PER_IMG + t;
    float b0 = boxes_all[g * 4 + 0];
    float b1 = boxes_all[g * 4 + 1];
    float b2 = boxes_all[g * 4 + 2];
    float b3 = boxes_all[g * 4 + 3];
    sbx1[t] = b0; sby1[t] = b1; sbx2[t] = b2; sby2[t] = b3;
    float area = fmaxf(b2 - b0, 0.f) * fmaxf(b3 - b1, 0.f);
    sarea[t] = area;
    float scr = scr_all[g];
    __syncthreads();

    for (int it = 0; it < IMTOP; it++) {
        sval[t] = scr;
        sidx[t] = t;
        __syncthreads();
        for (int off = PER_IMG / 2; off > 0; off >>= 1) {
            if (t < off) {
                float v2 = sval[t + off]; int i2 = sidx[t + off];
                float v1 = sval[t];       int i1 = sidx[t];
                if (v2 > v1 || (v2 == v1 && i2 < i1)) { sval[t] = v2; sidx[t] = i2; }
            }
            __syncthreads();
        }
        int sel = sidx[0];
        float s = sval[0];
        float cx1 = sbx1[sel], cy1 = sby1[sel], cx2 = sbx2[sel], cy2 = sby2[sel];
        float ai = sarea[sel];
        if (t == 0) {
            out[(img * IMTOP + it) * 4 + 0] = cx1;
            out[(img * IMTOP + it) * 4 + 1] = cy1;
            out[(img * IMTOP + it) * 4 + 2] = cx2;
            out[(img * IMTOP + it) * 4 + 3] = cy2;
            out[NIMG * IMTOP * 4 + img * IMTOP + it] = fmaxf(s, -1.0f);
            float validf = (s > SCORE_THR) ? 1.0f : 0.0f;
            out[NIMG * IMTOP * 5 + img * IMTOP + it] = validf;
            out[NIMG * IMTOP * 6 + img * IMTOP + it] = validf;
        }
        float xx1 = fmaxf(cx1, b0), yy1 = fmaxf(cy1, b1);
        float xx2 = fminf(cx2, b2), yy2 = fminf(cy2, b3);
        float inter = fmaxf(xx2 - xx1, 0.f) * fmaxf(yy2 - yy1, 0.f);
        float iou = inter / (ai + area - inter + 1e-6f);
        if (iou > IOU_THR || t == sel) scr = -__builtin_inff();
        __syncthreads();
    }
}

// ----------------------------------------------------------------------------
extern "C" void kernel_launch(void* const* d_in, const int* in_sizes, int n_in,
                              void* d_out, int out_size, void* d_ws, size_t ws_size,
                              hipStream_t stream)
{
    const float* prop  = (const float*)d_in[0];
    const int*   imidx = (const int*)d_in[1];
    const float* f0    = (const float*)d_in[2];
    const float* f1    = (const float*)d_in[3];
    const float* f2    = (const float*)d_in[4];
    const float* f3    = (const float*)d_in[5];
    const int*   imsz  = (const int*)d_in[6];
    const float* fc6w  = (const float*)d_in[7];
    const float* fc6b  = (const float*)d_in[8];
    const float* fc7w  = (const float*)d_in[9];
    const float* fc7b  = (const float*)d_in[10];
    const float* clsw  = (const float*)d_in[11];
    const float* clsb  = (const float*)d_in[12];
    const float* regw  = (const float*)d_in[13];
    const float* regb  = (const float*)d_in[14];

    char* w = (char*)d_ws;
    _Float16* feat_hi = (_Float16*)w;  w += (size_t)N_ROI * KFEAT * 2;   // 51.4 MB
    _Float16* feat_lo = (_Float16*)w;  w += (size_t)N_ROI * KFEAT * 2;
    _Float16* w6hi    = (_Float16*)w;  w += (size_t)CMID * KFEAT * 2;    // 25.7 MB
    _Float16* w6lo    = (_Float16*)w;  w += (size_t)CMID * KFEAT * 2;
    _Float16* w7hi    = (_Float16*)w;  w += (size_t)CMID * CMID * 2;     // 2.1 MB
    _Float16* w7lo    = (_Float16*)w;  w += (size_t)CMID * CMID * 2;
    _Float16* h1hi    = (_Float16*)w;  w += (size_t)N_ROI * CMID * 2;    // 4.2 MB
    _Float16* h1lo    = (_Float16*)w;  w += (size_t)N_ROI * CMID * 2;
    float*    h2      = (float*)w;     w += (size_t)N_ROI * CMID * 4;    // 8.4 MB
    float*    part    = (float*)w;     w += (size_t)N_ROI * CMID * 4 * 4; // 33.6 MB (4 slabs)
    float*    boxes_all = (float*)w;   w += (size_t)N_ROI * 4 * 4;
    float*    scr_all = (float*)w;     w += (size_t)N_ROI * 4;

    // weight conversion + permutation
    convert_fc6w_kernel<<<(CMID * KFEAT) / 256, 256, 0, stream>>>(fc6w, w6hi, w6lo);
    convert_w_kernel<<<(CMID * CMID) / 256, 256, 0, stream>>>(fc7w, w7hi, w7lo);

    // roi align -> split features (K-order bin*256+c)
    roi_align_kernel<<<N_ROI, 256, 0, stream>>>(prop, imidx, f0, f1, f2, f3,
                                                feat_hi, feat_lo);

    // FC6: M=2048, N=1024, K=12544, split-K=4
    gemm3_kernel<<<dim3(N_ROI / 128, CMID / 128, 4), 256, 0, stream>>>(
        feat_hi, feat_lo, w6hi, w6lo, part, N_ROI, CMID, KFEAT, KFEAT / 4);
    reduce_fc6_kernel<<<(N_ROI * CMID) / 256, 256, 0, stream>>>(part, fc6b, h1hi, h1lo);

    // FC7: M=2048, N=1024, K=1024, split-K=2
    gemm3_kernel<<<dim3(N_ROI / 128, CMID / 128, 2), 256, 0, stream>>>(
        h1hi, h1lo, w7hi, w7lo, part, N_ROI, CMID, CMID, CMID / 2);
    reduce_fc7_kernel<<<(N_ROI * CMID) / 256, 256, 0, stream>>>(part, fc7b, h2);

    head_kernel<<<N_ROI, 64, 0, stream>>>(h2, prop, imidx, imsz, clsw, clsb,
                                          regw, regb, boxes_all, scr_all);

    nms_kernel<<<NIMG, PER_IMG, 0, stream>>>(boxes_all, scr_all, (float*)d_out);
}

// Round 4
// 1031.682 us; speedup vs baseline: 1.6991x; 1.1698x over previous
//
#include <hip/hip_runtime.h>
#include <hip/hip_bf16.h>
#include <cmath>

#define N_ROI 2048
#define PER_IMG 256
#define NIMG 8
#define NCH 256
#define ROUT 7
#define KFEAT (NCH * ROUT * ROUT)   // 12544
#define CMID 1024
#define IMSZ 640
#define IMTOP 100
#define SCORE_THR 0.05f
#define IOU_THR 0.5f
#define BBOX_CLAMP 4.135166556742356f   // log(1000/16)

#define HW_TOT 34000   // 25600+6400+1600+400 per image

typedef _Float16 half8 __attribute__((ext_vector_type(8)));
typedef float floatx4 __attribute__((ext_vector_type(4)));

#define GLLDS16(gp, lp) \
  __builtin_amdgcn_global_load_lds((const __attribute__((address_space(1))) unsigned int*)(gp), \
                                   (__attribute__((address_space(3))) unsigned int*)(lp), 16, 0, 0)

// ----------------------------------------------------------------------------
// Weight conversion: fp32 -> (hi fp16, lo fp16 scaled by 2^12).
// fc6 variant permutes K from c*49+bin to bin*256+c (matches feat layout).
// ----------------------------------------------------------------------------
__global__ __launch_bounds__(256) void convert_fc6w_kernel(
    const float* __restrict__ w, _Float16* __restrict__ whi, _Float16* __restrict__ wlo)
{
    int idx = blockIdx.x * 256 + threadIdx.x;          // n*12544 + bin*256 + c
    int rem = idx % KFEAT;
    int n = idx / KFEAT;
    int c = rem & 255;
    int bin = rem >> 8;                                 // < 49
    float v = w[(size_t)n * KFEAT + c * (ROUT * ROUT) + bin];
    _Float16 h = (_Float16)v;
    whi[idx] = h;
    wlo[idx] = (_Float16)((v - (float)h) * 4096.0f);
}

__global__ __launch_bounds__(256) void convert_w_kernel(
    const float* __restrict__ w, _Float16* __restrict__ whi, _Float16* __restrict__ wlo)
{
    int idx = blockIdx.x * 256 + threadIdx.x;
    float v = w[idx];
    _Float16 h = (_Float16)v;
    whi[idx] = h;
    wlo[idx] = (_Float16)((v - (float)h) * 4096.0f);
}

// ----------------------------------------------------------------------------
// NCHW -> NHWC transpose for one pyramid level (fp32, LDS 32c x 64hw tiles).
// dst index = ((img*34000 + cumhw + hw)*256 + c). Dedicated region, no overlay.
// ----------------------------------------------------------------------------
__global__ __launch_bounds__(256) void transpose_nhwc_kernel(
    const float* __restrict__ src, float* __restrict__ dst, int HW, int cumhw)
{
    __shared__ float t[32][65];
    const int tid = threadIdx.x;
    const int img = blockIdx.z;
    const int hw0 = blockIdx.x * 64;
    const int c0 = blockIdx.y * 32;

    const int lane = tid & 63;
    const int row = tid >> 6;            // 0..3
    const int hw = hw0 + lane;
    const float* s = src + ((size_t)img * NCH + c0) * HW;
    if (hw < HW) {
#pragma unroll
        for (int i = 0; i < 8; i++) {
            int cl = row * 8 + i;
            t[cl][lane] = s[(size_t)cl * HW + hw];
        }
    }
    __syncthreads();
    const int cl = tid & 31;
    const int wl = tid >> 5;             // 0..7
#pragma unroll
    for (int j = 0; j < 8; j++) {
        int hwl = wl + j * 8;
        int hw2 = hw0 + hwl;
        if (hw2 < HW)
            dst[((size_t)img * HW_TOT + cumhw + hw2) * NCH + c0 + cl] = t[cl][hwl];
    }
}

// ----------------------------------------------------------------------------
// RoI Align gather from NHWC: block per RoI, thread = channel. Geometry
// (corner offsets + bilinear weights) precomputed in LDS by threads 0..48.
// ----------------------------------------------------------------------------
__global__ __launch_bounds__(256) void roi_gather_nhwc_kernel(
    const float* __restrict__ prop, const int* __restrict__ imidx,
    const float* __restrict__ nhwc,
    _Float16* __restrict__ feat_hi, _Float16* __restrict__ feat_lo)
{
    __shared__ int  o00[49], o01[49], o10[49], o11[49];
    __shared__ float w00[49], w01[49], w10[49], w11[49];

    const int roi = blockIdx.x;
    const int tid = threadIdx.x;

    if (tid < 49) {
        const int cumhw_[4] = {0, 25600, 32000, 33600};
        const float x1 = prop[roi * 4 + 0], y1 = prop[roi * 4 + 1];
        const float x2 = prop[roi * 4 + 2], y2 = prop[roi * 4 + 3];
        const float area = fmaxf(x2 - x1, 0.f) * fmaxf(y2 - y1, 0.f);
        float lf = floorf(4.0f + log2f(sqrtf(area) / 224.0f + 1e-8f));
        lf = fminf(fmaxf(lf, 2.0f), 5.0f);
        const int lvl = (int)lf - 2;
        const int stride = 4 << lvl;
        const int W = IMSZ / stride;
        const float sc = 1.0f / (float)stride;
        const int img = imidx[roi];
        const int imgbase = (img * HW_TOT + cumhw_[lvl]) * NCH;
        const float stepx = (x2 - x1) * sc * (1.0f / ROUT);
        const float stepy = (y2 - y1) * sc * (1.0f / ROUT);
        const int by = tid / 7, bx = tid % 7;
        float py = y1 * sc + ((float)by + 0.5f) * stepy;
        float px = x1 * sc + ((float)bx + 0.5f) * stepx;
        float y = fminf(fmaxf(py, 0.f), (float)(W - 1));
        float x = fminf(fmaxf(px, 0.f), (float)(W - 1));
        float y0f = floorf(y), x0f = floorf(x);
        int yi0 = (int)y0f, xi0 = (int)x0f;
        int yi1 = min(yi0 + 1, W - 1), xi1 = min(xi0 + 1, W - 1);
        float fy = y - y0f, fx = x - x0f;
        o00[tid] = imgbase + (yi0 * W + xi0) * NCH;
        o01[tid] = imgbase + (yi0 * W + xi1) * NCH;
        o10[tid] = imgbase + (yi1 * W + xi0) * NCH;
        o11[tid] = imgbase + (yi1 * W + xi1) * NCH;
        w00[tid] = (1.f - fy) * (1.f - fx);
        w01[tid] = (1.f - fy) * fx;
        w10[tid] = fy * (1.f - fx);
        w11[tid] = fy * fx;
    }
    __syncthreads();

    const int c = tid;
    _Float16* ohi = feat_hi + (size_t)roi * KFEAT + c;
    _Float16* olo = feat_lo + (size_t)roi * KFEAT + c;
#pragma unroll 7
    for (int b = 0; b < 49; b++) {
        float v = nhwc[o00[b] + c] * w00[b]
                + nhwc[o01[b] + c] * w01[b]
                + nhwc[o10[b] + c] * w10[b]
                + nhwc[o11[b] + c] * w11[b];
        _Float16 h = (_Float16)v;
        ohi[b * NCH] = h;
        olo[b * NCH] = (_Float16)((v - (float)h) * 4096.0f);
    }
}

// ----------------------------------------------------------------------------
// Fallback RoI Align (NCHW direct gather) — identical to the round-2 version.
// ----------------------------------------------------------------------------
__global__ __launch_bounds__(256) void roi_align_kernel(
    const float* __restrict__ prop, const int* __restrict__ imidx,
    const float* __restrict__ f0, const float* __restrict__ f1,
    const float* __restrict__ f2, const float* __restrict__ f3,
    _Float16* __restrict__ feat_hi, _Float16* __restrict__ feat_lo)
{
    const int roi = blockIdx.x;
    const int c = threadIdx.x;
    const float x1 = prop[roi * 4 + 0], y1 = prop[roi * 4 + 1];
    const float x2 = prop[roi * 4 + 2], y2 = prop[roi * 4 + 3];
    const float area = fmaxf(x2 - x1, 0.f) * fmaxf(y2 - y1, 0.f);
    float lf = floorf(4.0f + log2f(sqrtf(area) / 224.0f + 1e-8f));
    lf = fminf(fmaxf(lf, 2.0f), 5.0f);
    const int lvl = (int)lf - 2;
    const int stride = 4 << lvl;
    const int H = IMSZ / stride;
    const int W = H;
    const float* fm = (lvl == 0) ? f0 : (lvl == 1) ? f1 : (lvl == 2) ? f2 : f3;
    const float sc = 1.0f / (float)stride;
    const int img = imidx[roi];
    const float* base = fm + ((size_t)(img * NCH + c)) * (size_t)(H * W);
    const float stepx = (x2 - x1) * sc * (1.0f / ROUT);
    const float stepy = (y2 - y1) * sc * (1.0f / ROUT);
    const float ox = x1 * sc, oy = y1 * sc;
    _Float16* ohi = feat_hi + (size_t)roi * KFEAT + c;
    _Float16* olo = feat_lo + (size_t)roi * KFEAT + c;

    for (int by = 0; by < ROUT; by++) {
        float py = oy + ((float)by + 0.5f) * stepy;
        float y = fminf(fmaxf(py, 0.f), (float)(H - 1));
        float y0 = floorf(y);
        int yi0 = (int)y0;
        int yi1 = min(yi0 + 1, H - 1);
        float fy = y - y0;
        for (int bx = 0; bx < ROUT; bx++) {
            float px = ox + ((float)bx + 0.5f) * stepx;
            float x = fminf(fmaxf(px, 0.f), (float)(W - 1));
            float x0 = floorf(x);
            int xi0 = (int)x0;
            int xi1 = min(xi0 + 1, W - 1);
            float fx = x - x0;
            float v00 = base[yi0 * W + xi0];
            float v01 = base[yi0 * W + xi1];
            float v10 = base[yi1 * W + xi0];
            float v11 = base[yi1 * W + xi1];
            float v = v00 * ((1.f - fy) * (1.f - fx))
                    + v01 * ((1.f - fy) * fx)
                    + v10 * (fy * (1.f - fx))
                    + v11 * (fy * fx);
            int bin = by * ROUT + bx;
            _Float16 h = (_Float16)v;
            ohi[bin * 256] = h;
            olo[bin * 256] = (_Float16)((v - (float)h) * 4096.0f);
        }
    }
}

// ----------------------------------------------------------------------------
// Compensated-fp16 GEMM — EXACT round-2 version (replay-proven): A staged in
// LDS via global_load_lds, B fragments direct from global.
// ----------------------------------------------------------------------------
__global__ __launch_bounds__(256, 2) void gemm3_kernel(
    const _Float16* __restrict__ Ahi, const _Float16* __restrict__ Alo,
    const _Float16* __restrict__ Bhi, const _Float16* __restrict__ Blo,
    float* __restrict__ part, int M, int N, int K, int Ks)
{
    __shared__ __align__(16) char lds[16384];   // [2 planes][128 rows][64 B]
    const int tid = threadIdx.x;
    const int wave = tid >> 6;
    const int lane = tid & 63;
    const int quad = lane >> 4;
    const int l16 = lane & 15;
    const int wm = wave >> 1, wn = wave & 1;
    const int bm = blockIdx.x * 128;
    const int bn = blockIdx.y * 128;
    const long kbase = (long)blockIdx.z * Ks;

    floatx4 acc1[4][4];
    floatx4 acc2[4][4];
#pragma unroll
    for (int i = 0; i < 4; i++)
#pragma unroll
        for (int j = 0; j < 4; j++) { acc1[i][j] = (floatx4)0.0f; acc2[i][j] = (floatx4)0.0f; }

    const int slot = lane & 3;
    const int srow = lane >> 2;          // 0..15 within a 16-row staging group

    for (int k0 = 0; k0 < Ks; k0 += 32) {
        __syncthreads();
        // ---- stage A hi/lo tile (128 rows x 32 k) via global_load_lds ----
#pragma unroll
        for (int p = 0; p < 2; p++) {
            const _Float16* src = p ? Alo : Ahi;
#pragma unroll
            for (int jj = 0; jj < 2; jj++) {
                int r0 = wave * 32 + jj * 16;
                int r = r0 + srow;
                int cch = slot ^ ((r >> 1) & 3);
                const _Float16* g = src + (size_t)(bm + r) * K + kbase + k0 + cch * 8;
                char* l = lds + p * 8192 + r0 * 64;
                GLLDS16(g, l);
            }
        }
        // ---- B fragments direct from global (overlap with LDS fill) ----
        half8 bh[4], bl[4];
#pragma unroll
        for (int nt = 0; nt < 4; nt++) {
            size_t boff = (size_t)(bn + wn * 64 + nt * 16 + l16) * K + kbase + k0 + quad * 8;
            bh[nt] = *(const half8*)(Bhi + boff);
            bl[nt] = *(const half8*)(Blo + boff);
        }
        __syncthreads();
        // ---- A fragments from LDS ----
        half8 ah[4], al[4];
#pragma unroll
        for (int mt = 0; mt < 4; mt++) {
            int r = wm * 64 + mt * 16 + l16;
            int s = quad ^ ((r >> 1) & 3);
            ah[mt] = *(const half8*)(lds + r * 64 + s * 16);
            al[mt] = *(const half8*)(lds + 8192 + r * 64 + s * 16);
        }
        // ---- 48 MFMAs ----
#pragma unroll
        for (int mt = 0; mt < 4; mt++)
#pragma unroll
            for (int nt = 0; nt < 4; nt++) {
                acc1[mt][nt] = __builtin_amdgcn_mfma_f32_16x16x32_f16(ah[mt], bh[nt], acc1[mt][nt], 0, 0, 0);
                acc2[mt][nt] = __builtin_amdgcn_mfma_f32_16x16x32_f16(ah[mt], bl[nt], acc2[mt][nt], 0, 0, 0);
                acc2[mt][nt] = __builtin_amdgcn_mfma_f32_16x16x32_f16(al[mt], bh[nt], acc2[mt][nt], 0, 0, 0);
            }
    }

    // ---- epilogue: fp32 partials ----
    float* op = part + (size_t)blockIdx.z * M * N;
#pragma unroll
    for (int mt = 0; mt < 4; mt++)
#pragma unroll
        for (int nt = 0; nt < 4; nt++) {
            int n = bn + wn * 64 + nt * 16 + l16;
            int mb = bm + wm * 64 + mt * 16 + quad * 4;
#pragma unroll
            for (int r = 0; r < 4; r++)
                op[(size_t)(mb + r) * N + n] = acc1[mt][nt][r] + acc2[mt][nt][r] * (1.0f / 4096.0f);
        }
}

// ----------------------------------------------------------------------------
// Reductions over split-K partials.
// ----------------------------------------------------------------------------
__global__ __launch_bounds__(256) void reduce_fc6_kernel(
    const float* __restrict__ part, const float* __restrict__ bias,
    _Float16* __restrict__ h1hi, _Float16* __restrict__ h1lo)
{
    const int MN = N_ROI * CMID;
    int idx = blockIdx.x * 256 + threadIdx.x;
    float v = part[idx] + part[idx + MN] + part[idx + 2 * MN] + part[idx + 3 * MN]
            + bias[idx & (CMID - 1)];
    v = fmaxf(v, 0.f);
    _Float16 h = (_Float16)v;
    h1hi[idx] = h;
    h1lo[idx] = (_Float16)((v - (float)h) * 4096.0f);
}

__global__ __launch_bounds__(256) void reduce_fc7_kernel(
    const float* __restrict__ part, const float* __restrict__ bias,
    float* __restrict__ h2)
{
    const int MN = N_ROI * CMID;
    int idx = blockIdx.x * 256 + threadIdx.x;
    float v = part[idx] + part[idx + MN] + bias[idx & (CMID - 1)];
    h2[idx] = fmaxf(v, 0.f);
}

// ----------------------------------------------------------------------------
// Heads: one wave per RoI.
// ----------------------------------------------------------------------------
__global__ __launch_bounds__(64) void head_kernel(
    const float* __restrict__ h2, const float* __restrict__ prop,
    const int* __restrict__ imidx, const int* __restrict__ imsizes,
    const float* __restrict__ cls_w, const float* __restrict__ cls_b,
    const float* __restrict__ reg_w, const float* __restrict__ reg_b,
    float* __restrict__ boxes_all, float* __restrict__ scr_all)
{
    const int roi = blockIdx.x;
    const int l = threadIdx.x;
    const float* h = h2 + (size_t)roi * CMID;
    float a0 = 0.f, a1 = 0.f, r0 = 0.f, r1 = 0.f, r2 = 0.f, r3 = 0.f;
    for (int k = l; k < CMID; k += 64) {
        float hv = h[k];
        a0 += hv * cls_w[k];
        a1 += hv * cls_w[CMID + k];
        r0 += hv * reg_w[4 * CMID + k];
        r1 += hv * reg_w[5 * CMID + k];
        r2 += hv * reg_w[6 * CMID + k];
        r3 += hv * reg_w[7 * CMID + k];
    }
    for (int off = 32; off > 0; off >>= 1) {
        a0 += __shfl_down(a0, off);
        a1 += __shfl_down(a1, off);
        r0 += __shfl_down(r0, off);
        r1 += __shfl_down(r1, off);
        r2 += __shfl_down(r2, off);
        r3 += __shfl_down(r3, off);
    }
    if (l == 0) {
        float l0 = a0 + cls_b[0], l1 = a1 + cls_b[1];
        float scr = 1.0f / (1.0f + expf(l0 - l1));
        float dx = (r0 + reg_b[4]) / 10.0f;
        float dy = (r1 + reg_b[5]) / 10.0f;
        float dw = (r2 + reg_b[6]) / 5.0f;
        float dh = (r3 + reg_b[7]) / 5.0f;
        float x1 = prop[roi * 4 + 0], y1 = prop[roi * 4 + 1];
        float x2 = prop[roi * 4 + 2], y2 = prop[roi * 4 + 3];
        float w = x2 - x1, hh = y2 - y1;
        float cx = x1 + 0.5f * w, cy = y1 + 0.5f * hh;
        float pcx = dx * w + cx, pcy = dy * hh + cy;
        float pw = w * expf(fminf(dw, BBOX_CLAMP));
        float ph = hh * expf(fminf(dh, BBOX_CLAMP));
        int img = imidx[roi];
        float szh = (float)imsizes[img * 2 + 0];
        float szw = (float)imsizes[img * 2 + 1];
        float bx1 = fminf(fmaxf(pcx - 0.5f * pw, 0.f), szw);
        float bx2 = fminf(fmaxf(pcx + 0.5f * pw, 0.f), szw);
        float by1 = fminf(fmaxf(pcy - 0.5f * ph, 0.f), szh);
        float by2 = fminf(fmaxf(pcy + 0.5f * ph, 0.f), szh);
        bool keep = (scr > SCORE_THR) && (bx2 - bx1 >= 1.0f) && (by2 - by1 >= 1.0f);
        boxes_all[roi * 4 + 0] = bx1;
        boxes_all[roi * 4 + 1] = by1;
        boxes_all[roi * 4 + 2] = bx2;
        boxes_all[roi * 4 + 3] = by2;
        scr_all[roi] = keep ? scr : -1.0f;
    }
}

// ----------------------------------------------------------------------------
// NMS: one block per image, 100 sequential argmax selections.
// ----------------------------------------------------------------------------
__global__ __launch_bounds__(PER_IMG) void nms_kernel(
    const float* __restrict__ boxes_all, const float* __restrict__ scr_all,
    float* __restrict__ out)
{
    const int img = blockIdx.x;
    const int t = threadIdx.x;
    __shared__ float sbx1[PER_IMG], sby1[PER_IMG], sbx2[PER_IMG], sby2[PER_IMG];
    __shared__ float sarea[PER_IMG];
    __shared__ float sval[PER_IMG];
    __shared__ int sidx[PER_IMG];

    const int g = img * PER_IMG + t;
    float b0 = boxes_all[g * 4 + 0];
    float b1 = boxes_all[g * 4 + 1];
    float b2 = boxes_all[g * 4 + 2];
    float b3 = boxes_all[g * 4 + 3];
    sbx1[t] = b0; sby1[t] = b1; sbx2[t] = b2; sby2[t] = b3;
    float area = fmaxf(b2 - b0, 0.f) * fmaxf(b3 - b1, 0.f);
    sarea[t] = area;
    float scr = scr_all[g];
    __syncthreads();

    for (int it = 0; it < IMTOP; it++) {
        sval[t] = scr;
        sidx[t] = t;
        __syncthreads();
        for (int off = PER_IMG / 2; off > 0; off >>= 1) {
            if (t < off) {
                float v2 = sval[t + off]; int i2 = sidx[t + off];
                float v1 = sval[t];       int i1 = sidx[t];
                if (v2 > v1 || (v2 == v1 && i2 < i1)) { sval[t] = v2; sidx[t] = i2; }
            }
            __syncthreads();
        }
        int sel = sidx[0];
        float s = sval[0];
        float cx1 = sbx1[sel], cy1 = sby1[sel], cx2 = sbx2[sel], cy2 = sby2[sel];
        float ai = sarea[sel];
        if (t == 0) {
            out[(img * IMTOP + it) * 4 + 0] = cx1;
            out[(img * IMTOP + it) * 4 + 1] = cy1;
            out[(img * IMTOP + it) * 4 + 2] = cx2;
            out[(img * IMTOP + it) * 4 + 3] = cy2;
            out[NIMG * IMTOP * 4 + img * IMTOP + it] = fmaxf(s, -1.0f);
            float validf = (s > SCORE_THR) ? 1.0f : 0.0f;
            out[NIMG * IMTOP * 5 + img * IMTOP + it] = validf;
            out[NIMG * IMTOP * 6 + img * IMTOP + it] = validf;
        }
        float xx1 = fmaxf(cx1, b0), yy1 = fmaxf(cy1, b1);
        float xx2 = fminf(cx2, b2), yy2 = fminf(cy2, b3);
        float inter = fmaxf(xx2 - xx1, 0.f) * fmaxf(yy2 - yy1, 0.f);
        float iou = inter / (ai + area - inter + 1e-6f);
        if (iou > IOU_THR || t == sel) scr = -__builtin_inff();
        __syncthreads();
    }
}

// ----------------------------------------------------------------------------
extern "C" void kernel_launch(void* const* d_in, const int* in_sizes, int n_in,
                              void* d_out, int out_size, void* d_ws, size_t ws_size,
                              hipStream_t stream)
{
    const float* prop  = (const float*)d_in[0];
    const int*   imidx = (const int*)d_in[1];
    const float* f0    = (const float*)d_in[2];
    const float* f1    = (const float*)d_in[3];
    const float* f2    = (const float*)d_in[4];
    const float* f3    = (const float*)d_in[5];
    const int*   imsz  = (const int*)d_in[6];
    const float* fc6w  = (const float*)d_in[7];
    const float* fc6b  = (const float*)d_in[8];
    const float* fc7w  = (const float*)d_in[9];
    const float* fc7b  = (const float*)d_in[10];
    const float* clsw  = (const float*)d_in[11];
    const float* clsb  = (const float*)d_in[12];
    const float* regw  = (const float*)d_in[13];
    const float* regb  = (const float*)d_in[14];

    // ---- base layout: identical to round 2 (no overlays, ~208.8 MB) ----
    char* w = (char*)d_ws;
    _Float16* feat_hi = (_Float16*)w;  w += (size_t)N_ROI * KFEAT * 2;   // 51.4 MB
    _Float16* feat_lo = (_Float16*)w;  w += (size_t)N_ROI * KFEAT * 2;
    _Float16* w6hi    = (_Float16*)w;  w += (size_t)CMID * KFEAT * 2;    // 25.7 MB
    _Float16* w6lo    = (_Float16*)w;  w += (size_t)CMID * KFEAT * 2;
    _Float16* w7hi    = (_Float16*)w;  w += (size_t)CMID * CMID * 2;     // 2.1 MB
    _Float16* w7lo    = (_Float16*)w;  w += (size_t)CMID * CMID * 2;
    _Float16* h1hi    = (_Float16*)w;  w += (size_t)N_ROI * CMID * 2;    // 4.2 MB
    _Float16* h1lo    = (_Float16*)w;  w += (size_t)N_ROI * CMID * 2;
    float*    h2      = (float*)w;     w += (size_t)N_ROI * CMID * 4;    // 8.4 MB
    float*    part    = (float*)w;     w += (size_t)N_ROI * CMID * 4 * 4; // 33.6 MB (4 slabs)
    float*    boxes_all = (float*)w;   w += (size_t)N_ROI * 4 * 4;
    float*    scr_all = (float*)w;     w += (size_t)N_ROI * 4;

    // ---- dedicated NHWC region appended AFTER everything (no aliasing) ----
    const size_t NHWC_BYTES = (size_t)NIMG * HW_TOT * NCH * 4;  // 278.5 MB
    const size_t base_bytes = (size_t)(w - (char*)d_ws);
    const bool use_nhwc = ws_size >= base_bytes + NHWC_BYTES;
    float* nhwc = (float*)w;

    // weight conversion + permutation (round-2 order: first)
    convert_fc6w_kernel<<<(CMID * KFEAT) / 256, 256, 0, stream>>>(fc6w, w6hi, w6lo);
    convert_w_kernel<<<(CMID * CMID) / 256, 256, 0, stream>>>(fc7w, w7hi, w7lo);

    if (use_nhwc) {
        transpose_nhwc_kernel<<<dim3(400, 8, NIMG), 256, 0, stream>>>(f0, nhwc, 25600, 0);
        transpose_nhwc_kernel<<<dim3(100, 8, NIMG), 256, 0, stream>>>(f1, nhwc, 6400, 25600);
        transpose_nhwc_kernel<<<dim3(25, 8, NIMG), 256, 0, stream>>>(f2, nhwc, 1600, 32000);
        transpose_nhwc_kernel<<<dim3(7, 8, NIMG), 256, 0, stream>>>(f3, nhwc, 400, 33600);
        roi_gather_nhwc_kernel<<<N_ROI, 256, 0, stream>>>(prop, imidx, nhwc,
                                                          feat_hi, feat_lo);
    } else {
        roi_align_kernel<<<N_ROI, 256, 0, stream>>>(prop, imidx, f0, f1, f2, f3,
                                                    feat_hi, feat_lo);
    }

    // FC6: M=2048, N=1024, K=12544, split-K=4
    gemm3_kernel<<<dim3(N_ROI / 128, CMID / 128, 4), 256, 0, stream>>>(
        feat_hi, feat_lo, w6hi, w6lo, part, N_ROI, CMID, KFEAT, KFEAT / 4);
    reduce_fc6_kernel<<<(N_ROI * CMID) / 256, 256, 0, stream>>>(part, fc6b, h1hi, h1lo);

    // FC7: M=2048, N=1024, K=1024, split-K=2
    gemm3_kernel<<<dim3(N_ROI / 128, CMID / 128, 2), 256, 0, stream>>>(
        h1hi, h1lo, w7hi, w7lo, part, N_ROI, CMID, CMID, CMID / 2);
    reduce_fc7_kernel<<<(N_ROI * CMID) / 256, 256, 0, stream>>>(part, fc7b, h2);

    head_kernel<<<N_ROI, 64, 0, stream>>>(h2, prop, imidx, imsz, clsw, clsb,
                                          regw, regb, boxes_all, scr_all);

    nms_kernel<<<NIMG, PER_IMG, 0, stream>>>(boxes_all, scr_all, (float*)d_out);
}